// Round 1
// baseline (848.770 us; speedup 1.0000x reference)
//
#include <hip/hip_runtime.h>
#include <math.h>

#define T 8
#define NI 20000
#define NK 50000
#define F 128
#define H 256
#define O 128
#define E 500000
#define MAXS 256          // slot cap per timestep (E[slots]=25, Poisson tail negligible)
#define BMW 1568          // ceil(NK/32) rounded up

// ---------------- workspace layout (bytes) ----------------
#define OFF_CNT2   0                       // T ints
#define OFF_ITEMS  32                      // T*MAXS ints
#define OFF_CNT1   (32 + T*MAXS*4)         // T*MAXS ints
#define OFF_SUMX2  (OFF_CNT1 + T*MAXS*4)   // T*F floats
#define OFF_HSUM   (OFF_SUMX2 + T*F*4)     // T*H floats
#define OFF_O      (OFF_HSUM + T*H*4)      // T*O floats
#define OFF_SUM1   (OFF_O + T*O*4)         // T*MAXS*F floats
#define WS_USED    (OFF_SUM1 + (size_t)T*MAXS*F*4)

// K1: scan e2_dst for edges into target; record src items (slots) and
// accumulate sum of x_item[src] rows (for the h_inf mean term).
__global__ void k_find_e2(const int* __restrict__ e2_src, const int* __restrict__ e2_dst,
                          const float* __restrict__ x_item, const int* __restrict__ target_p,
                          int* __restrict__ cnt2, int* __restrict__ items,
                          float* __restrict__ sum_x2) {
    long gid = (long)blockIdx.x * 256 + threadIdx.x;
    if (gid >= (long)T * E) return;
    int t = (int)(gid / E);
    long j = gid - (long)t * E;
    int target = *target_p;
    if (e2_dst[(long)t * E + j] == target) {
        int src = e2_src[(long)t * E + j];
        int pos = atomicAdd(&cnt2[t], 1);
        if (pos < MAXS) items[t * MAXS + pos] = src;
        const float* xr = x_item + ((long)t * NK + src) * F;
        float* acc = sum_x2 + t * F;
        for (int f = 0; f < F; ++f) atomicAdd(&acc[f], xr[f]);
    }
}

// K2: scan e1_dst; for edges whose dst is one of this timestep's items,
// accumulate x_inf[src] into that slot's sum and bump its count.
// LDS bitmap over NK items makes the per-edge test O(1).
__global__ void k_scan_e1(const int* __restrict__ e1_src, const int* __restrict__ e1_dst,
                          const float* __restrict__ x_inf,
                          const int* __restrict__ cnt2, const int* __restrict__ items,
                          int* __restrict__ cnt1, float* __restrict__ sum1) {
    __shared__ int s_items[MAXS];
    __shared__ unsigned s_bm[BMW];
    int t = blockIdx.y;
    int ns = min(cnt2[t], MAXS);
    for (int i = threadIdx.x; i < BMW; i += 256) s_bm[i] = 0u;
    __syncthreads();
    for (int i = threadIdx.x; i < ns; i += 256) {
        int it = items[t * MAXS + i];
        s_items[i] = it;
        atomicOr(&s_bm[it >> 5], 1u << (it & 31));
    }
    __syncthreads();
    long j = (long)blockIdx.x * 256 + threadIdx.x;
    if (j >= E) return;
    int d = e1_dst[(long)t * E + j];
    if (!((s_bm[d >> 5] >> (d & 31)) & 1u)) return;
    int src = e1_src[(long)t * E + j];
    const float* xr = x_inf + ((long)t * NI + src) * F;
    for (int i = 0; i < ns; ++i) {
        if (s_items[i] == d) {
            atomicAdd(&cnt1[t * MAXS + i], 1);
            float* acc = sum1 + ((long)t * MAXS + i) * F;
            for (int f = 0; f < F; ++f) atomicAdd(&acc[f], xr[f]);
        }
    }
}

// K3: per slot, h_item = relu(mean_e1 @ W1a_l.T + b1a_l + x_item[item] @ W1a_r.T);
// accumulate Sigma_slots h_item into hsum[t].
__global__ void k_hitem(const float* __restrict__ x_item,
                        const float* __restrict__ W1a_l, const float* __restrict__ b1a_l,
                        const float* __restrict__ W1a_r,
                        const int* __restrict__ cnt2, const int* __restrict__ items,
                        const int* __restrict__ cnt1, const float* __restrict__ sum1,
                        float* __restrict__ hsum) {
    int t = blockIdx.y, slot = blockIdx.x;
    int ns = min(cnt2[t], MAXS);
    if (slot >= ns) return;
    __shared__ float z1[F], xk[F];
    int item = items[t * MAXS + slot];
    float inv = 1.0f / fmaxf((float)cnt1[t * MAXS + slot], 1.0f);
    if (threadIdx.x < F) {
        z1[threadIdx.x] = sum1[((long)t * MAXS + slot) * F + threadIdx.x] * inv;
        xk[threadIdx.x] = x_item[((long)t * NK + item) * F + threadIdx.x];
    }
    __syncthreads();
    int h = threadIdx.x;  // 256 threads == H
    float acc = b1a_l[h];
    const float* wl = W1a_l + h * F;
    const float* wr = W1a_r + h * F;
    for (int f = 0; f < F; ++f) acc += z1[f] * wl[f] + xk[f] * wr[f];
    acc = fmaxf(acc, 0.0f);
    atomicAdd(&hsum[t * H + h], acc);
}

// K4: per timestep t: h_inf[target] then o[t] = mean_h @ W2b_l.T + b2b_l + h_inf @ W2b_r.T
__global__ void k_layer2(const float* __restrict__ x_inf, const int* __restrict__ target_p,
                         const float* __restrict__ W1b_l, const float* __restrict__ b1b_l,
                         const float* __restrict__ W1b_r,
                         const float* __restrict__ W2b_l, const float* __restrict__ b2b_l,
                         const float* __restrict__ W2b_r,
                         const int* __restrict__ cnt2, const float* __restrict__ sum_x2,
                         const float* __restrict__ hsum, float* __restrict__ o) {
    int t = blockIdx.x;
    __shared__ float z2[F], xt[F], hinf[H], mh[H];
    int target = *target_p;
    float c2 = fmaxf((float)cnt2[t], 1.0f);
    if (threadIdx.x < F) {
        z2[threadIdx.x] = sum_x2[t * F + threadIdx.x] / c2;
        xt[threadIdx.x] = x_inf[((long)t * NI + target) * F + threadIdx.x];
    }
    __syncthreads();
    int h = threadIdx.x;
    {
        float acc = b1b_l[h];
        const float* wl = W1b_l + h * F;
        const float* wr = W1b_r + h * F;
        for (int f = 0; f < F; ++f) acc += z2[f] * wl[f] + xt[f] * wr[f];
        hinf[h] = fmaxf(acc, 0.0f);
        mh[h] = hsum[t * H + h] / c2;
    }
    __syncthreads();
    if (threadIdx.x < O) {
        int f = threadIdx.x;
        float acc = b2b_l[f];
        const float* wl = W2b_l + f * H;
        const float* wr = W2b_r + f * H;
        for (int k = 0; k < H; ++k) acc += mh[k] * wl[k] + hinf[k] * wr[k];
        o[t * O + f] = acc;
    }
}

// K5: GRU over T steps + attention + prediction head -> scalar
__global__ void k_head(const float* __restrict__ o,
                       const float* __restrict__ W_ih, const float* __restrict__ W_hh,
                       const float* __restrict__ b_ih, const float* __restrict__ b_hh,
                       const float* __restrict__ W_att, const float* __restrict__ b_att,
                       const float* __restrict__ W_p1, const float* __restrict__ b_p1,
                       const float* __restrict__ W_p2, const float* __restrict__ b_p2,
                       float* __restrict__ out) {
    __shared__ float x[O], h[H], rnn[T][H], tmp[H], att[T], hid[128];
    int tid = threadIdx.x;  // 256 threads
    h[tid] = 0.0f;
    __syncthreads();
    for (int t = 0; t < T; ++t) {
        if (tid < O) x[tid] = o[t * O + tid];
        __syncthreads();
        float gi_r = b_ih[tid], gi_z = b_ih[H + tid], gi_n = b_ih[2 * H + tid];
        const float* wr_ = W_ih + (long)tid * O;
        const float* wz_ = W_ih + (long)(H + tid) * O;
        const float* wn_ = W_ih + (long)(2 * H + tid) * O;
        for (int k = 0; k < O; ++k) {
            gi_r += wr_[k] * x[k]; gi_z += wz_[k] * x[k]; gi_n += wn_[k] * x[k];
        }
        float gh_r = b_hh[tid], gh_z = b_hh[H + tid], gh_n = b_hh[2 * H + tid];
        const float* vr = W_hh + (long)tid * H;
        const float* vz = W_hh + (long)(H + tid) * H;
        const float* vn = W_hh + (long)(2 * H + tid) * H;
        for (int k = 0; k < H; ++k) {
            gh_r += vr[k] * h[k]; gh_z += vz[k] * h[k]; gh_n += vn[k] * h[k];
        }
        float r = 1.0f / (1.0f + expf(-(gi_r + gh_r)));
        float z = 1.0f / (1.0f + expf(-(gi_z + gh_z)));
        float n = tanhf(gi_n + r * gh_n);
        float hn = (1.0f - z) * n + z * h[tid];
        __syncthreads();              // everyone done reading h
        h[tid] = hn;
        rnn[t][tid] = hn;
        __syncthreads();
    }
    if (tid < T) {
        float a = b_att[0];
        for (int k = 0; k < H; ++k) a += W_att[k] * rnn[tid][k];
        att[tid] = a;
    }
    __syncthreads();
    if (tid == 0) {
        float m = att[0];
        for (int t = 1; t < T; ++t) m = fmaxf(m, att[t]);
        float s = 0.0f;
        for (int t = 0; t < T; ++t) { att[t] = expf(att[t] - m); s += att[t]; }
        for (int t = 0; t < T; ++t) att[t] /= s;
    }
    __syncthreads();
    float ctx = 0.0f;
    for (int t = 0; t < T; ++t) ctx += att[t] * rnn[t][tid];
    tmp[tid] = ctx;
    __syncthreads();
    if (tid < 128) {
        float a = b_p1[tid];
        const float* w = W_p1 + (long)tid * H;
        for (int k = 0; k < H; ++k) a += w[k] * tmp[k];
        hid[tid] = fmaxf(a, 0.0f);
    }
    __syncthreads();
    if (tid == 0) {
        float s = b_p2[0];
        for (int k = 0; k < 128; ++k) s += W_p2[k] * hid[k];
        out[0] = s;
    }
}

extern "C" void kernel_launch(void* const* d_in, const int* in_sizes, int n_in,
                              void* d_out, int out_size, void* d_ws, size_t ws_size,
                              hipStream_t stream) {
    const float* x_inf  = (const float*)d_in[0];
    const float* x_item = (const float*)d_in[1];
    const int* e1_src = (const int*)d_in[2];
    const int* e1_dst = (const int*)d_in[3];
    const int* e2_src = (const int*)d_in[4];
    const int* e2_dst = (const int*)d_in[5];
    const int* target_p = (const int*)d_in[6];
    const float* W1a_l = (const float*)d_in[7];
    const float* b1a_l = (const float*)d_in[8];
    const float* W1a_r = (const float*)d_in[9];
    const float* W1b_l = (const float*)d_in[10];
    const float* b1b_l = (const float*)d_in[11];
    const float* W1b_r = (const float*)d_in[12];
    // d_in[13..15]: W2a_* (dead code in the model)
    const float* W2b_l = (const float*)d_in[16];
    const float* b2b_l = (const float*)d_in[17];
    const float* W2b_r = (const float*)d_in[18];
    const float* W_ih = (const float*)d_in[19];
    const float* W_hh = (const float*)d_in[20];
    const float* b_ih = (const float*)d_in[21];
    const float* b_hh = (const float*)d_in[22];
    const float* W_att = (const float*)d_in[23];
    const float* b_att = (const float*)d_in[24];
    const float* W_p1 = (const float*)d_in[25];
    const float* b_p1 = (const float*)d_in[26];
    const float* W_p2 = (const float*)d_in[27];
    const float* b_p2 = (const float*)d_in[28];
    float* out = (float*)d_out;

    char* ws = (char*)d_ws;
    int*   cnt2   = (int*)(ws + OFF_CNT2);
    int*   items  = (int*)(ws + OFF_ITEMS);
    int*   cnt1   = (int*)(ws + OFF_CNT1);
    float* sum_x2 = (float*)(ws + OFF_SUMX2);
    float* hsum   = (float*)(ws + OFF_HSUM);
    float* o      = (float*)(ws + OFF_O);
    float* sum1   = (float*)(ws + OFF_SUM1);

    hipMemsetAsync(d_ws, 0, WS_USED, stream);

    long total = (long)T * E;
    int nb1 = (int)((total + 255) / 256);
    k_find_e2<<<nb1, 256, 0, stream>>>(e2_src, e2_dst, x_item, target_p, cnt2, items, sum_x2);

    dim3 g2((E + 255) / 256, T);
    k_scan_e1<<<g2, 256, 0, stream>>>(e1_src, e1_dst, x_inf, cnt2, items, cnt1, sum1);

    dim3 g3(MAXS, T);
    k_hitem<<<g3, 256, 0, stream>>>(x_item, W1a_l, b1a_l, W1a_r, cnt2, items, cnt1, sum1, hsum);

    k_layer2<<<T, 256, 0, stream>>>(x_inf, target_p, W1b_l, b1b_l, W1b_r,
                                    W2b_l, b2b_l, W2b_r, cnt2, sum_x2, hsum, o);

    k_head<<<1, 256, 0, stream>>>(o, W_ih, W_hh, b_ih, b_hh, W_att, b_att,
                                  W_p1, b_p1, W_p2, b_p2, out);
}

// Round 2
// 676.753 us; speedup vs baseline: 1.2542x; 1.2542x over previous
//
#include <hip/hip_runtime.h>
#include <math.h>

#define T 8
#define NI 20000
#define NK 50000
#define F 128
#define H 256
#define O 128
#define E 500000
#define G3 (3*H)          // 768
#define MAXS 256          // slot cap per timestep (E[slots]=25)
#define BMW 1568          // ceil(NK/32)
#define NB 8              // persistent GRU blocks
#define RPB 32            // h-indices per GRU block (H/NB)

// ---------------- workspace layout (bytes) ----------------
#define OFF_CNT2   0                        // T ints
#define OFF_ITEMS  32                       // T*MAXS ints
#define OFF_CNT1   (32 + T*MAXS*4)          // T*MAXS ints
#define OFF_SUMX2  (OFF_CNT1 + T*MAXS*4)    // T*F floats
#define OFF_HSUM   (OFF_SUMX2 + T*F*4)      // T*H floats
#define OFF_O      (OFF_HSUM + T*H*4)       // T*O floats
#define OFF_GI     (OFF_O + T*O*4)          // T*G3 floats
#define OFF_RNN    (OFF_GI + T*G3*4)        // T*H floats
#define OFF_BAR    (OFF_RNN + T*H*4)        // 16 ints
#define OFF_SUM1   (OFF_BAR + 64)           // T*MAXS*F floats
#define WS_USED    (OFF_SUM1 + (size_t)T*MAXS*F*4)

// K1: scan e2_dst for edges into target; record src items (slots) and
// accumulate sum of x_item[src] rows (for the h_inf mean term).
__global__ void k_find_e2(const int* __restrict__ e2_src, const int* __restrict__ e2_dst,
                          const float* __restrict__ x_item, const int* __restrict__ target_p,
                          int* __restrict__ cnt2, int* __restrict__ items,
                          float* __restrict__ sum_x2) {
    int t = blockIdx.y;
    long j = (long)blockIdx.x * 256 + threadIdx.x;
    if (j >= E) return;
    int target = *target_p;
    if (e2_dst[(long)t * E + j] == target) {
        int src = e2_src[(long)t * E + j];
        int pos = atomicAdd(&cnt2[t], 1);
        if (pos < MAXS) items[t * MAXS + pos] = src;
        const float* xr = x_item + ((long)t * NK + src) * F;
        float* acc = sum_x2 + t * F;
        for (int f = 0; f < F; ++f) atomicAdd(&acc[f], xr[f]);
    }
}

// K2: scan e1_dst; accumulate x_inf[src] into matching item slot.
__global__ void k_scan_e1(const int* __restrict__ e1_src, const int* __restrict__ e1_dst,
                          const float* __restrict__ x_inf,
                          const int* __restrict__ cnt2, const int* __restrict__ items,
                          int* __restrict__ cnt1, float* __restrict__ sum1) {
    __shared__ int s_items[MAXS];
    __shared__ unsigned s_bm[BMW];
    int t = blockIdx.y;
    int ns = min(cnt2[t], MAXS);
    for (int i = threadIdx.x; i < BMW; i += 256) s_bm[i] = 0u;
    __syncthreads();
    for (int i = threadIdx.x; i < ns; i += 256) {
        int it = items[t * MAXS + i];
        s_items[i] = it;
        atomicOr(&s_bm[it >> 5], 1u << (it & 31));
    }
    __syncthreads();
    long j = (long)blockIdx.x * 256 + threadIdx.x;
    if (j >= E) return;
    int d = e1_dst[(long)t * E + j];
    if (!((s_bm[d >> 5] >> (d & 31)) & 1u)) return;
    int src = e1_src[(long)t * E + j];
    const float* xr = x_inf + ((long)t * NI + src) * F;
    for (int i = 0; i < ns; ++i) {
        if (s_items[i] == d) {
            atomicAdd(&cnt1[t * MAXS + i], 1);
            float* acc = sum1 + ((long)t * MAXS + i) * F;
            for (int f = 0; f < F; ++f) atomicAdd(&acc[f], xr[f]);
        }
    }
}

// K3: per slot, h_item = relu(mean @ W1a_l.T + b1a_l + x_item @ W1a_r.T); sum into hsum.
__global__ void k_hitem(const float* __restrict__ x_item,
                        const float* __restrict__ W1a_l, const float* __restrict__ b1a_l,
                        const float* __restrict__ W1a_r,
                        const int* __restrict__ cnt2, const int* __restrict__ items,
                        const int* __restrict__ cnt1, const float* __restrict__ sum1,
                        float* __restrict__ hsum) {
    int t = blockIdx.y, slot = blockIdx.x;
    int ns = min(cnt2[t], MAXS);
    if (slot >= ns) return;
    __shared__ float z1[F], xk[F];
    int item = items[t * MAXS + slot];
    float inv = 1.0f / fmaxf((float)cnt1[t * MAXS + slot], 1.0f);
    if (threadIdx.x < F) {
        z1[threadIdx.x] = sum1[((long)t * MAXS + slot) * F + threadIdx.x] * inv;
        xk[threadIdx.x] = x_item[((long)t * NK + item) * F + threadIdx.x];
    }
    __syncthreads();
    int h = threadIdx.x;  // 256 == H
    float acc = b1a_l[h];
    const float* wl = W1a_l + h * F;
    const float* wr = W1a_r + h * F;
    for (int f = 0; f < F; ++f) acc += z1[f] * wl[f] + xk[f] * wr[f];
    acc = fmaxf(acc, 0.0f);
    atomicAdd(&hsum[t * H + h], acc);
}

// K4: per t: h_inf[target], then o[t] = mean_h @ W2b_l.T + b2b_l + h_inf @ W2b_r.T
__global__ void k_layer2(const float* __restrict__ x_inf, const int* __restrict__ target_p,
                         const float* __restrict__ W1b_l, const float* __restrict__ b1b_l,
                         const float* __restrict__ W1b_r,
                         const float* __restrict__ W2b_l, const float* __restrict__ b2b_l,
                         const float* __restrict__ W2b_r,
                         const int* __restrict__ cnt2, const float* __restrict__ sum_x2,
                         const float* __restrict__ hsum, float* __restrict__ o) {
    int t = blockIdx.x;
    __shared__ float z2[F], xt[F], hinf[H], mh[H];
    int target = *target_p;
    float c2 = fmaxf((float)cnt2[t], 1.0f);
    if (threadIdx.x < F) {
        z2[threadIdx.x] = sum_x2[t * F + threadIdx.x] / c2;
        xt[threadIdx.x] = x_inf[((long)t * NI + target) * F + threadIdx.x];
    }
    __syncthreads();
    int h = threadIdx.x;
    {
        float acc = b1b_l[h];
        const float* wl = W1b_l + h * F;
        const float* wr = W1b_r + h * F;
        for (int f = 0; f < F; ++f) acc += z2[f] * wl[f] + xt[f] * wr[f];
        hinf[h] = fmaxf(acc, 0.0f);
        mh[h] = hsum[t * H + h] / c2;
    }
    __syncthreads();
    if (threadIdx.x < O) {
        int f = threadIdx.x;
        float acc = b2b_l[f];
        const float* wl = W2b_l + f * H;
        const float* wr = W2b_r + f * H;
        for (int k = 0; k < H; ++k) acc += mh[k] * wl[k] + hinf[k] * wr[k];
        o[t * O + f] = acc;
    }
}

// K5a: gi[t] = W_ih @ o[t] + b_ih for all t (parallel; wave per row).
__global__ void k_gi(const float* __restrict__ o, const float* __restrict__ W_ih,
                     const float* __restrict__ b_ih, float* __restrict__ gi) {
    int t = blockIdx.y;
    int wv = threadIdx.x >> 6, lane = threadIdx.x & 63;
    int row = blockIdx.x * 4 + wv;  // 0..767
    const float* w = W_ih + (long)row * O;
    const float* x = o + t * O;
    float s = w[lane] * x[lane] + w[lane + 64] * x[lane + 64];
    for (int off = 32; off; off >>= 1) s += __shfl_down(s, off);
    if (lane == 0) gi[t * G3 + row] = s + b_ih[row];
}

// K5b: persistent 8-block GRU. Block b owns h-indices [32b,32b+32); its 96
// W_hh rows live in LDS. h exchanged via agent-scope atomics + spin barrier.
// Block 0 runs attention + prediction head after the last step.
__global__ void __launch_bounds__(256, 1)
k_gru(const float* __restrict__ gi, const float* __restrict__ W_hh,
      const float* __restrict__ b_hh,
      const float* __restrict__ W_att, const float* __restrict__ b_att,
      const float* __restrict__ W_p1, const float* __restrict__ b_p1,
      const float* __restrict__ W_p2, const float* __restrict__ b_p2,
      float* __restrict__ rnn, int* __restrict__ bar, float* __restrict__ out) {
    __shared__ float w[3 * RPB][H];   // 96 KiB
    __shared__ float h[H];
    __shared__ float srnn[T][H];      // 8 KiB (block 0 tail)
    __shared__ float satt[T], tmp[H], hid[128];
    int b = blockIdx.x, tid = threadIdx.x;
    // load W_hh slice (coalesced)
    for (int idx = tid; idx < 3 * RPB * H; idx += 256) {
        int r = idx >> 8, k = idx & 255;
        int g = r / RPB, j = r - g * RPB;
        w[r][k] = W_hh[((long)(g * H + b * RPB + j)) * H + k];
    }
    h[tid] = 0.0f;
    __syncthreads();
    int wv = tid >> 6, lane = tid & 63;
    for (int t = 0; t < T; ++t) {
        for (int j = wv; j < RPB; j += 4) {
            float sr = 0.f, sz = 0.f, sn = 0.f;
            for (int c = 0; c < 4; ++c) {
                int k = lane + 64 * c;
                float hk = h[k];
                sr += w[j][k] * hk;
                sz += w[RPB + j][k] * hk;
                sn += w[2 * RPB + j][k] * hk;
            }
            for (int off = 32; off; off >>= 1) {
                sr += __shfl_down(sr, off);
                sz += __shfl_down(sz, off);
                sn += __shfl_down(sn, off);
            }
            if (lane == 0) {
                int i = b * RPB + j;
                float gir = gi[t * G3 + i];
                float giz = gi[t * G3 + H + i];
                float gin = gi[t * G3 + 2 * H + i];
                float r = 1.0f / (1.0f + expf(-(gir + sr + b_hh[i])));
                float z = 1.0f / (1.0f + expf(-(giz + sz + b_hh[H + i])));
                float n = tanhf(gin + r * (sn + b_hh[2 * H + i]));
                float hn = (1.0f - z) * n + z * h[i];
                __hip_atomic_store(&rnn[t * H + i], hn, __ATOMIC_RELAXED,
                                   __HIP_MEMORY_SCOPE_AGENT);
            }
        }
        __syncthreads();
        if (tid == 0) {
            __threadfence();
            __hip_atomic_fetch_add(&bar[t], 1, __ATOMIC_RELEASE, __HIP_MEMORY_SCOPE_AGENT);
            while (__hip_atomic_load(&bar[t], __ATOMIC_ACQUIRE, __HIP_MEMORY_SCOPE_AGENT) < NB)
                __builtin_amdgcn_s_sleep(1);
            __threadfence();
        }
        __syncthreads();
        h[tid] = __hip_atomic_load(&rnn[t * H + tid], __ATOMIC_RELAXED,
                                   __HIP_MEMORY_SCOPE_AGENT);
        __syncthreads();
    }
    if (b != 0) return;
    // ---- attention + head (block 0) ----
    for (int idx = tid; idx < T * H; idx += 256)
        srnn[idx >> 8][idx & 255] = __hip_atomic_load(&rnn[idx], __ATOMIC_RELAXED,
                                                      __HIP_MEMORY_SCOPE_AGENT);
    __syncthreads();
    {   // att scores: 32 lanes per t
        int tt = tid >> 5, l32 = tid & 31;
        float a = 0.f;
        for (int c = 0; c < 8; ++c) {
            int k = l32 + 32 * c;
            a += W_att[k] * srnn[tt][k];
        }
        for (int off = 16; off; off >>= 1) a += __shfl_down(a, off, 32);
        if (l32 == 0) satt[tt] = a + b_att[0];
    }
    __syncthreads();
    if (tid == 0) {
        float m = satt[0];
        for (int t = 1; t < T; ++t) m = fmaxf(m, satt[t]);
        float s = 0.f;
        for (int t = 0; t < T; ++t) { satt[t] = expf(satt[t] - m); s += satt[t]; }
        for (int t = 0; t < T; ++t) satt[t] /= s;
    }
    __syncthreads();
    {
        float ctx = 0.f;
        for (int t = 0; t < T; ++t) ctx += satt[t] * srnn[t][tid];
        tmp[tid] = ctx;
    }
    __syncthreads();
    if (tid < 128) {
        float a = b_p1[tid];
        const float* wp = W_p1 + (long)tid * H;
        for (int k = 0; k < H; ++k) a += wp[k] * tmp[k];
        hid[tid] = fmaxf(a, 0.0f);
    }
    __syncthreads();
    if (tid == 0) {
        float s = b_p2[0];
        for (int k = 0; k < 128; ++k) s += W_p2[k] * hid[k];
        out[0] = s;
    }
}

extern "C" void kernel_launch(void* const* d_in, const int* in_sizes, int n_in,
                              void* d_out, int out_size, void* d_ws, size_t ws_size,
                              hipStream_t stream) {
    const float* x_inf  = (const float*)d_in[0];
    const float* x_item = (const float*)d_in[1];
    const int* e1_src = (const int*)d_in[2];
    const int* e1_dst = (const int*)d_in[3];
    const int* e2_src = (const int*)d_in[4];
    const int* e2_dst = (const int*)d_in[5];
    const int* target_p = (const int*)d_in[6];
    const float* W1a_l = (const float*)d_in[7];
    const float* b1a_l = (const float*)d_in[8];
    const float* W1a_r = (const float*)d_in[9];
    const float* W1b_l = (const float*)d_in[10];
    const float* b1b_l = (const float*)d_in[11];
    const float* W1b_r = (const float*)d_in[12];
    const float* W2b_l = (const float*)d_in[16];
    const float* b2b_l = (const float*)d_in[17];
    const float* W2b_r = (const float*)d_in[18];
    const float* W_ih = (const float*)d_in[19];
    const float* W_hh = (const float*)d_in[20];
    const float* b_ih = (const float*)d_in[21];
    const float* b_hh = (const float*)d_in[22];
    const float* W_att = (const float*)d_in[23];
    const float* b_att = (const float*)d_in[24];
    const float* W_p1 = (const float*)d_in[25];
    const float* b_p1 = (const float*)d_in[26];
    const float* W_p2 = (const float*)d_in[27];
    const float* b_p2 = (const float*)d_in[28];
    float* out = (float*)d_out;

    char* ws = (char*)d_ws;
    int*   cnt2   = (int*)(ws + OFF_CNT2);
    int*   items  = (int*)(ws + OFF_ITEMS);
    int*   cnt1   = (int*)(ws + OFF_CNT1);
    float* sum_x2 = (float*)(ws + OFF_SUMX2);
    float* hsum   = (float*)(ws + OFF_HSUM);
    float* o      = (float*)(ws + OFF_O);
    float* gi     = (float*)(ws + OFF_GI);
    float* rnn    = (float*)(ws + OFF_RNN);
    int*   bar    = (int*)(ws + OFF_BAR);
    float* sum1   = (float*)(ws + OFF_SUM1);

    hipMemsetAsync(d_ws, 0, WS_USED, stream);

    dim3 g1((E + 255) / 256, T);
    k_find_e2<<<g1, 256, 0, stream>>>(e2_src, e2_dst, x_item, target_p, cnt2, items, sum_x2);

    dim3 g2((E + 255) / 256, T);
    k_scan_e1<<<g2, 256, 0, stream>>>(e1_src, e1_dst, x_inf, cnt2, items, cnt1, sum1);

    dim3 g3(MAXS, T);
    k_hitem<<<g3, 256, 0, stream>>>(x_item, W1a_l, b1a_l, W1a_r, cnt2, items, cnt1, sum1, hsum);

    k_layer2<<<T, 256, 0, stream>>>(x_inf, target_p, W1b_l, b1b_l, W1b_r,
                                    W2b_l, b2b_l, W2b_r, cnt2, sum_x2, hsum, o);

    dim3 g5(G3 / 4, T);
    k_gi<<<g5, 256, 0, stream>>>(o, W_ih, b_ih, gi);

    k_gru<<<NB, 256, 0, stream>>>(gi, W_hh, b_hh, W_att, b_att,
                                  W_p1, b_p1, W_p2, b_p2, rnn, bar, out);
}